// Round 1
// baseline (1717.936 us; speedup 1.0000x reference)
//
#include <hip/hip_runtime.h>
#include <math.h>

#define Nn 512
#define Mm 32000
#define Bb 64
#define Tt 256
#define Gg 16     // blocks in recursion kernel
#define RPB 32    // rows of A per block

typedef short v8s __attribute__((ext_vector_type(8)));   // 8 bf16 (4 VGPR) MFMA frag
typedef float v4f __attribute__((ext_vector_type(4)));   // MFMA accumulator
typedef unsigned short us4 __attribute__((ext_vector_type(4)));

__device__ inline unsigned short f2bf(float f) {  // RNE float->bf16
  unsigned int u = __float_as_uint(f);
  unsigned int r = u + 0x7FFFu + ((u >> 16) & 1u);
  return (unsigned short)(r >> 16);
}

// ---- logsumexp over columns of trans (dim 0) ----
__global__ void k_col_lse(const float* __restrict__ trans, float* __restrict__ lseA) {
  int k = blockIdx.x, tid = threadIdx.x;
  float m = -3.0e38f, s = 0.f;
  for (int j = tid; j < Nn; j += 256) {
    float v = trans[j * Nn + k];
    if (v > m) { s = s * __expf(m - v) + 1.f; m = v; }
    else       { s += __expf(v - m); }
  }
  __shared__ float sm[256], ss[256];
  sm[tid] = m; ss[tid] = s; __syncthreads();
  for (int off = 128; off; off >>= 1) {
    if (tid < off) {
      float m2 = sm[tid+off], s2 = ss[tid+off], m1 = sm[tid], s1 = ss[tid];
      float mm = fmaxf(m1, m2);
      sm[tid] = mm; ss[tid] = s1 * __expf(m1 - mm) + s2 * __expf(m2 - mm);
    }
    __syncthreads();
  }
  if (tid == 0) lseA[k] = sm[0] + __logf(ss[0]);
}

// ---- A[j][k] = exp(trans - col_lse) as bf16, row-major ----
__global__ void k_writeA(const float* __restrict__ trans, const float* __restrict__ lseA,
                         unsigned short* __restrict__ Abf) {
  int j = blockIdx.x, tid = threadIdx.x;
  for (int k = tid; k < Nn; k += 256)
    Abf[j * Nn + k] = f2bf(__expf(trans[j * Nn + k] - lseA[k]));
}

// ---- pi = softmax(prior) ----
__global__ void k_pi(const float* __restrict__ prior, float* __restrict__ pi) {
  int tid = threadIdx.x;
  __shared__ float sm[512];
  float v = prior[tid];
  sm[tid] = v; __syncthreads();
  for (int off = 256; off; off >>= 1) { if (tid < off) sm[tid] = fmaxf(sm[tid], sm[tid+off]); __syncthreads(); }
  float mx = sm[0]; __syncthreads();
  sm[tid] = __expf(v - mx); __syncthreads();
  for (int off = 256; off; off >>= 1) { if (tid < off) sm[tid] += sm[tid+off]; __syncthreads(); }
  pi[tid] = __expf(v - mx) / sm[0];
}

// ---- fused: row-lse of emis (dim 1) + gather Pem[t][j][b] = exp(emis[j,x[b,t]] - lse[j]) ----
__global__ void k_emis(const float* __restrict__ emis, const int* __restrict__ x,
                       float* __restrict__ Pem) {
  int j = blockIdx.x, tid = threadIdx.x;
  const float* row = emis + (size_t)j * Mm;
  float m = -3.0e38f, s = 0.f;
  for (int i = tid; i < Mm; i += 256) {
    float v = row[i];
    if (v > m) { s = s * __expf(m - v) + 1.f; m = v; }
    else       { s += __expf(v - m); }
  }
  __shared__ float sm[256], ss[256];
  sm[tid] = m; ss[tid] = s; __syncthreads();
  for (int off = 128; off; off >>= 1) {
    if (tid < off) {
      float m2 = sm[tid+off], s2 = ss[tid+off], m1 = sm[tid], s1 = ss[tid];
      float mm = fmaxf(m1, m2);
      sm[tid] = mm; ss[tid] = s1 * __expf(m1 - mm) + s2 * __expf(m2 - mm);
    }
    __syncthreads();
  }
  float lse = sm[0] + __logf(ss[0]);
  // gather: idx = t*64 + b; row j stays L1/L2-hot
  for (int r = 0; r < (Bb * Tt) / 256; ++r) {
    int idx = r * 256 + tid;
    int t = idx >> 6, b = idx & 63;
    int mv = x[b * Tt + t];
    Pem[(size_t)t * (Nn * Bb) + j * Bb + b] = __expf(row[mv] - lse);
  }
}

// ---- custom grid barrier (monotonic counter, 16 co-resident blocks) ----
__device__ inline void gbar(int* bar, int target) {
  __syncthreads();                       // drains vmcnt: block's stores are in L2 (L1 write-through)
  if (threadIdx.x == 0) {
    __builtin_amdgcn_fence(__ATOMIC_RELEASE, "agent");   // wb dirty L2 -> L3
    __hip_atomic_fetch_add(bar, 1, __ATOMIC_RELAXED, __HIP_MEMORY_SCOPE_AGENT);
    while (__hip_atomic_load(bar, __ATOMIC_RELAXED, __HIP_MEMORY_SCOPE_AGENT) < target)
      __builtin_amdgcn_s_sleep(1);
    __builtin_amdgcn_fence(__ATOMIC_ACQUIRE, "agent");   // inv L1+L2 so fresh alpha is read
  }
  __syncthreads();
}

// ---- recursion: 16 blocks x 4 waves; wave tile 16 rows x 32 batch; A frags in VGPRs ----
__global__ __launch_bounds__(256, 1) void k_fwd(
    const unsigned short* __restrict__ Abf, const float* __restrict__ Pem,
    const float* __restrict__ pi, const int* __restrict__ Tlen,
    unsigned short* __restrict__ a0, unsigned short* __restrict__ a1,
    float* __restrict__ out, int* __restrict__ bar)
{
  const int tid = threadIdx.x;
  const int w = tid >> 6, lane = tid & 63;
  const int rg = w >> 1, bg = w & 1;       // row-group, batch-group
  const int c = lane & 15, kq = lane >> 4; // MFMA lane coords
  const int jw = blockIdx.x * RPB + rg * 16;
  const int bw = bg * 32;

  // A fragments for this wave's 16 rows, all K=512 (static across all timesteps)
  // layout: A-frag lane l holds A[jw + (l&15)][kk*32 + (l>>4)*8 + e]
  v8s af[16];
  #pragma unroll
  for (int kk = 0; kk < 16; ++kk)
    af[kk] = *reinterpret_cast<const v8s*>(Abf + (size_t)(jw + c) * Nn + kk * 32 + kq * 8);

  v8s onef;                                 // all-ones A operand -> computes s[b] = sum_k alpha[k,b]
  #pragma unroll
  for (int e = 0; e < 8; ++e) onef[e] = (short)0x3F80;  // bf16 1.0

  const int Tb0 = Tlen[bw + c], Tb1 = Tlen[bw + 16 + c];
  float L0 = 0.f, L1 = 0.f;                 // per-col cumulative log-scale

  // alpha_0[b][j] = Pem[0][j][b] * pi[j]  (stored transposed [b][k] bf16)
  {
    const int jbase = blockIdx.x * RPB;
    for (int i = tid; i < RPB * Bb; i += 256) {
      int jj = jbase + (i >> 6), b = i & 63;
      a0[b * Nn + jj] = f2bf(Pem[jj * Bb + b] * pi[jj]);
    }
  }
  gbar(bar, Gg);

  unsigned short* abuf[2] = {a0, a1};
  for (int t = 1; t <= Tt; ++t) {
    const unsigned short* aprev = abuf[(t + 1) & 1];
    unsigned short* anext = abuf[t & 1];

    // prefetch emission probs for this step (independent of alpha)
    float pv0[4], pv1[4];
    if (t < Tt) {
      #pragma unroll
      for (int r = 0; r < 4; ++r) {
        int jr = jw + kq * 4 + r;
        pv0[r] = Pem[(size_t)t * (Nn * Bb) + jr * Bb + bw + c];
        pv1[r] = Pem[(size_t)t * (Nn * Bb) + jr * Bb + bw + 16 + c];
      }
    }

    // B fragments: alpha stored [b][k] so lane's 8 k-elems are contiguous
    v8s bfr0[16], bfr1[16];
    #pragma unroll
    for (int kk = 0; kk < 16; ++kk) {
      bfr0[kk] = *reinterpret_cast<const v8s*>(aprev + (size_t)(bw + c) * Nn + kk * 32 + kq * 8);
      bfr1[kk] = *reinterpret_cast<const v8s*>(aprev + (size_t)(bw + 16 + c) * Nn + kk * 32 + kq * 8);
    }

    v4f accs0 = {0.f,0.f,0.f,0.f}, accs1 = {0.f,0.f,0.f,0.f};
    v4f acc0  = {0.f,0.f,0.f,0.f}, acc1  = {0.f,0.f,0.f,0.f};
    if (t < Tt) {
      #pragma unroll
      for (int kk = 0; kk < 16; ++kk) {
        accs0 = __builtin_amdgcn_mfma_f32_16x16x32_bf16(onef,   bfr0[kk], accs0, 0, 0, 0);
        accs1 = __builtin_amdgcn_mfma_f32_16x16x32_bf16(onef,   bfr1[kk], accs1, 0, 0, 0);
        acc0  = __builtin_amdgcn_mfma_f32_16x16x32_bf16(af[kk], bfr0[kk], acc0,  0, 0, 0);
        acc1  = __builtin_amdgcn_mfma_f32_16x16x32_bf16(af[kk], bfr1[kk], acc1,  0, 0, 0);
      }
    } else {  // final pass: only need s[b] for T==TMAX outputs
      #pragma unroll
      for (int kk = 0; kk < 16; ++kk) {
        accs0 = __builtin_amdgcn_mfma_f32_16x16x32_bf16(onef, bfr0[kk], accs0, 0, 0, 0);
        accs1 = __builtin_amdgcn_mfma_f32_16x16x32_bf16(onef, bfr1[kk], accs1, 0, 0, 0);
      }
    }
    float s0 = accs0[0], s1 = accs1[0];  // all C rows equal for ones-MFMA; col = c

    // s = sum_j alpha_{t-1}[j,b]  =>  log_sums[b][t-1] = L + log s ; emit when T[b]-1 == t-1
    if (blockIdx.x == 0 && rg == 0 && kq == 0) {
      if (Tb0 == t) out[bw + c]      = L0 + __logf(s0);
      if (Tb1 == t) out[bw + 16 + c] = L1 + __logf(s1);
    }

    if (t == Tt) break;

    // alpha_t[j,b] = Pem * (A . alpha_{t-1}) / s   (C layout: col=lane&15, row=kq*4+reg)
    float inv0 = 1.f / s0, inv1 = 1.f / s1;
    int jr = jw + kq * 4;
    us4 p0, p1;
    #pragma unroll
    for (int r = 0; r < 4; ++r) {
      p0[r] = f2bf(acc0[r] * pv0[r] * inv0);
      p1[r] = f2bf(acc1[r] * pv1[r] * inv1);
    }
    *reinterpret_cast<us4*>(anext + (size_t)(bw + c) * Nn + jr)      = p0;
    *reinterpret_cast<us4*>(anext + (size_t)(bw + 16 + c) * Nn + jr) = p1;

    L0 += __logf(s0); L1 += __logf(s1);
    gbar(bar, Gg * (t + 1));
  }
}

extern "C" void kernel_launch(void* const* d_in, const int* in_sizes, int n_in,
                              void* d_out, int out_size, void* d_ws, size_t ws_size,
                              hipStream_t stream) {
  const int*   x     = (const int*)  d_in[0];
  const int*   Tlen  = (const int*)  d_in[1];
  const float* trans = (const float*)d_in[2];
  const float* emis  = (const float*)d_in[3];
  const float* prior = (const float*)d_in[4];
  float* out = (float*)d_out;

  char* w = (char*)d_ws;
  unsigned short* Abf = (unsigned short*)(w);                 // 512 KB  bf16 A[j][k]
  unsigned short* a0  = (unsigned short*)(w + (512 << 10));   // 64 KB   alpha ping [b][k]
  unsigned short* a1  = (unsigned short*)(w + (576 << 10));   // 64 KB   alpha pong
  float* lseA = (float*)(w + (640 << 10));                    // 2 KB
  float* pi   = (float*)(w + (644 << 10));                    // 2 KB
  int*   bar  = (int*)  (w + (648 << 10));                    // barrier counter
  float* Pem  = (float*)(w + (1024 << 10));                   // 32 MB  Pem[t][j][b] fp32

  hipMemsetAsync(bar, 0, 256, stream);
  k_col_lse<<<Nn, 256, 0, stream>>>(trans, lseA);
  k_writeA <<<Nn, 256, 0, stream>>>(trans, lseA, Abf);
  k_pi     <<<1,  Nn,  0, stream>>>(prior, pi);
  k_emis   <<<Nn, 256, 0, stream>>>(emis, x, Pem);
  k_fwd    <<<Gg, 256, 0, stream>>>(Abf, Pem, pi, Tlen, a0, a1, out, bar);
}